// Round 5
// baseline (530.013 us; speedup 1.0000x reference)
//
#include <hip/hip_runtime.h>
#include <math.h>

typedef float f32x4 __attribute__((ext_vector_type(4)));
typedef short bf16x8 __attribute__((ext_vector_type(8)));
typedef unsigned short u16;

#define ACT_P 296   // act pitch (u16): cols 0..255 = h/x, 256..287 = eta
#define OUTS_P 392  // out staging pitch (u16), 384 cols
#define XF_P 66     // xf pitch (f32)

__device__ __forceinline__ u16 f2bf(float f) {
    union { float f; unsigned u; } v; v.f = f;
    return (u16)((v.u + 0x7FFFu + ((v.u >> 16) & 1u)) >> 16);
}
__device__ __forceinline__ float bf2f(u16 h) {
    union { unsigned u; float f; } v; v.u = ((unsigned)h) << 16;
    return v.f;
}
__device__ __forceinline__ float splusf(float x) {
    return fmaxf(x, 0.f) + __logf(1.f + __expf(-fabsf(x)));
}

// ---------------------------------------------------------------------------
// setup: build masked bf16 weights (+padded Wo) and fused biases
// ---------------------------------------------------------------------------
__global__ __launch_bounds__(256) void setup_w(
    const float* __restrict__ Win, const float* __restrict__ bin,
    const float* __restrict__ Wctx, const float* __restrict__ bctx,
    const float* __restrict__ Wblk, const float* __restrict__ Wout,
    const float* __restrict__ bout,
    u16* __restrict__ W1, float* __restrict__ B1, u16* __restrict__ WB,
    u16* __restrict__ WO, float* __restrict__ BO)
{
    const long N1 = 8L * 256 * 96;
    const long N2 = 8L * 256;
    const long N3 = 8L * 4 * 256 * 256;
    const long N4 = 8L * 3072 * 256;
    const long N5 = 8L * 3072;
    const long tot = N1 + N2 + N3 + N4 + N5;
    for (long i = (long)blockIdx.x * blockDim.x + threadIdx.x; i < tot;
         i += (long)gridDim.x * blockDim.x) {
        long t = i;
        if (t < N1) {
            long l = t / (256 * 96); long r = t % (256 * 96);
            int j = (int)(r / 96), c = (int)(r % 96);
            float v;
            if (c < 64) v = Win[(l * 256 + j) * 64 + c] * (((j % 63) >= c) ? 1.f : 0.f);
            else        v = Wctx[(l * 256 + j) * 32 + (c - 64)];
            W1[i] = f2bf(v);
        } else if ((t -= N1) < N2) {
            B1[t] = bin[t] + bctx[t];
        } else if ((t -= N2) < N3) {
            int rr = (int)((t / 256) % 256);
            int c = (int)(t % 256);
            float v = Wblk[t] * (((rr % 63) >= (c % 63)) ? 1.f : 0.f);
            WB[t] = f2bf(v);
        } else if ((t -= N3) < N4) {
            long l = t / (3072 * 256); long r = t % (3072 * 256);
            int op = (int)(r / 256), j = (int)(r % 256);
            int fd = op / 48, mm = op % 48;
            float v = 0.f;
            if (mm < 47 && fd > (j % 63))
                v = Wout[(l * 3008 + (long)fd * 47 + mm) * 256 + j];
            WO[t] = f2bf(v);
        } else {
            t -= N4;
            long l = t / 3072; int op = (int)(t % 3072);
            int fd = op / 48, mm = op % 48;
            BO[t] = (mm < 47) ? bout[l * 3008 + (long)fd * 47 + mm] : 0.f;
        }
    }
}

// ---------------------------------------------------------------------------
// data stats: d_mean (65) + d_sq -> DM[0..64], DM[65]
// ---------------------------------------------------------------------------
__global__ __launch_bounds__(128) void dstat(const float* __restrict__ D,
                                             float* __restrict__ DM)
{
    int j = threadIdx.x;
    float s = 0.f, q = 0.f;
    if (j < 65) {
        for (int m = 0; m < 256; ++m) {
            float v = D[m * 65 + j];
            s += v; q += v * v;
        }
        DM[j] = s * (1.f / 256.f);
    }
    __shared__ float red[128];
    red[j] = q; __syncthreads();
    for (int st = 64; st > 0; st >>= 1) {
        if (j < st) red[j] += red[j + st];
        __syncthreads();
    }
    if (j == 0) DM[65] = red[0] * (1.f / 256.f);
}

// ---------------------------------------------------------------------------
// mid GEMM stage: 32 rows x 256 out-channels, K = NK*32.
// Weights streamed global->LDS double-buffered (pitch 40). Wave owns 32 ch.
// S1: k-slice 2 reads act cols 256..287 (eta).
// ---------------------------------------------------------------------------
template<int NK, bool S1>
__device__ __forceinline__ void mid_stage(
    const u16* __restrict__ Wsrc, int wpitch,
    u16* __restrict__ Wq0, u16* __restrict__ Wq1,
    const u16* __restrict__ act,
    int tid, int fr, int kg, int ch0, f32x4 (&acc)[2][2])
{
    const int swr = tid >> 1;
    const int swp = (tid & 1) << 4;
    const u16* gW = Wsrc + (size_t)swr * wpitch + swp;

    *(int4*)&Wq0[swr * 40 + swp]     = *(const int4*)(gW);
    *(int4*)&Wq0[swr * 40 + swp + 8] = *(const int4*)(gW + 8);

#pragma unroll
    for (int ks = 0; ks < NK; ++ks) {
        const u16* cbuf = (ks & 1) ? Wq1 : Wq0;
        u16*       nbuf = (ks & 1) ? Wq0 : Wq1;
        int4 p0, p1;
        const bool more = (ks + 1 < NK);
        if (more) {
            p0 = *(const int4*)(gW + (ks + 1) * 32);
            p1 = *(const int4*)(gW + (ks + 1) * 32 + 8);
        }
        __syncthreads();
        const int ao = S1 ? ((ks == 2) ? 256 : ks * 32) : ks * 32;
        bf16x8 wf0 = *(const bf16x8*)&cbuf[(ch0 + fr) * 40 + kg * 8];
        bf16x8 wf1 = *(const bf16x8*)&cbuf[(ch0 + 16 + fr) * 40 + kg * 8];
        bf16x8 af0 = *(const bf16x8*)&act[fr * ACT_P + ao + kg * 8];
        bf16x8 af1 = *(const bf16x8*)&act[(16 + fr) * ACT_P + ao + kg * 8];
        acc[0][0] = __builtin_amdgcn_mfma_f32_16x16x32_bf16(wf0, af0, acc[0][0], 0, 0, 0);
        acc[0][1] = __builtin_amdgcn_mfma_f32_16x16x32_bf16(wf0, af1, acc[0][1], 0, 0, 0);
        acc[1][0] = __builtin_amdgcn_mfma_f32_16x16x32_bf16(wf1, af0, acc[1][0], 0, 0, 0);
        acc[1][1] = __builtin_amdgcn_mfma_f32_16x16x32_bf16(wf1, af1, acc[1][1], 0, 0, 0);
        if (more) {
            *(int4*)&nbuf[swr * 40 + swp]     = p0;
            *(int4*)&nbuf[swr * 40 + swp + 8] = p1;
        }
    }
    __syncthreads();
}

// ---------------------------------------------------------------------------
// flow_all: the full 8-layer flow, one block per 32 batch rows (grid 256).
// Everything stays in LDS/regs; only weights stream from L2.
// ---------------------------------------------------------------------------
__global__ __launch_bounds__(512) void flow_all(
    const float* __restrict__ z, const float* __restrict__ eta,
    const u16* __restrict__ W1, const float* __restrict__ B1,
    const u16* __restrict__ WB, const float* __restrict__ bblk,
    const u16* __restrict__ WO, const float* __restrict__ BO,
    float* __restrict__ XC, float* __restrict__ LD)
{
    __shared__ u16 actS[32 * ACT_P];      // 18944 B
    __shared__ u16 Wb0[384 * 40];         // 30720 B
    __shared__ u16 Wb1[384 * 40];         // 30720 B
    __shared__ u16 outS[32 * OUTS_P];     // 25088 B
    __shared__ float xfA[32 * XF_P];      // 8448 B
    __shared__ float xfB[32 * XF_P];      // 8448 B
    __shared__ float ldpart[8][32];       // 1024 B
    __shared__ float ldtot[32];           // 128 B

    const int tid = threadIdx.x;
    const int lane = tid & 63;
    const int wv = tid >> 6;
    const int fr = lane & 15, kg = lane >> 4;
    const int b0 = blockIdx.x * 32;

    // init: eta -> act cols 256..287; z -> xfA (flipped); ldtot = 0
    for (int i = tid; i < 1024; i += 512) {
        int r = i >> 5, p = i & 31;
        actS[r * ACT_P + 256 + p] = f2bf(eta[(size_t)(b0 + r) * 32 + p]);
    }
    for (int i = tid; i < 2048; i += 512) {
        int r = i >> 6, ff = i & 63;
        xfA[r * XF_P + ff] = z[(size_t)(b0 + r) * 64 + (63 - ff)];
    }
    if (tid < 32) ldtot[tid] = 0.f;

    f32x4 H[2][2], T[2][2];
    const int ch0 = wv * 32;

    for (int l = 0; l < 8; ++l) {
        const float* xfC = (l & 1) ? xfB : xfA;
        float*       xfN = (l & 1) ? xfA : xfB;

        __syncthreads();
        // act cols 0..63 = bf16(current flipped x)
        for (int i = tid; i < 2048; i += 512) {
            int r = i >> 6, ff = i & 63;
            actS[r * ACT_P + ff] = f2bf(xfC[r * XF_P + ff]);
        }
        __syncthreads();

        // ---- mid stack (H in regs) ----
        const u16* WBl = WB + (size_t)l * 4 * 65536;
        const float* bbl = bblk + (size_t)l * 4 * 256;

        auto zeroT = [&]() {
#pragma unroll
            for (int m = 0; m < 2; ++m)
#pragma unroll
                for (int n = 0; n < 2; ++n) T[m][n] = (f32x4){0.f, 0.f, 0.f, 0.f};
        };
        auto epi = [&](const float* bias, int mode) {
#pragma unroll
            for (int m = 0; m < 2; ++m) {
                const int cb = ch0 + m * 16 + kg * 4;
                const float4 bs = *(const float4*)&bias[cb];
#pragma unroll
                for (int n = 0; n < 2; ++n) {
                    f32x4 v = T[m][n];
                    v[0] += bs.x; v[1] += bs.y; v[2] += bs.z; v[3] += bs.w;
                    if (mode == 0) H[m][n] = v;
                    if (mode == 2 || mode == 3) {
                        H[m][n][0] += v[0]; H[m][n][1] += v[1];
                        H[m][n][2] += v[2]; H[m][n][3] += v[3];
                        v = H[m][n];
                    }
                    short4 q;
                    if (mode != 3) {
                        q.x = (short)f2bf(fmaxf(v[0], 0.f));
                        q.y = (short)f2bf(fmaxf(v[1], 0.f));
                        q.z = (short)f2bf(fmaxf(v[2], 0.f));
                        q.w = (short)f2bf(fmaxf(v[3], 0.f));
                    } else {
                        q.x = (short)f2bf(v[0]); q.y = (short)f2bf(v[1]);
                        q.z = (short)f2bf(v[2]); q.w = (short)f2bf(v[3]);
                    }
                    *(short4*)&actS[(n * 16 + fr) * ACT_P + cb] = q;
                }
            }
        };

        zeroT();
        mid_stage<3, true >(W1 + (size_t)l * 256 * 96, 96, Wb0, Wb1, actS, tid, fr, kg, ch0, T);
        epi(B1 + l * 256, 0);
        zeroT();
        mid_stage<8, false>(WBl, 256, Wb0, Wb1, actS, tid, fr, kg, ch0, T);
        epi(bbl, 1);
        zeroT();
        mid_stage<8, false>(WBl + 65536, 256, Wb0, Wb1, actS, tid, fr, kg, ch0, T);
        epi(bbl + 256, 2);
        zeroT();
        mid_stage<8, false>(WBl + 2 * 65536, 256, Wb0, Wb1, actS, tid, fr, kg, ch0, T);
        epi(bbl + 2 * 256, 1);
        zeroT();
        mid_stage<8, false>(WBl + 3 * 65536, 256, Wb0, Wb1, actS, tid, fr, kg, ch0, T);
        epi(bbl + 3 * 256, 3);
        // act cols 0..255 now hold the out-GEMM input h (bf16)

        // ---- out phase: 8 chunks of 384 cols (8 features each) ----
        const u16* WOl = WO + (size_t)l * 3072 * 256;
        const float* BOl = BO + (size_t)l * 3072;

        for (int ch = 0; ch < 8; ++ch) {
            const u16* gq = WOl + ((size_t)(ch * 384 + (tid >> 2))) * 256 + (tid & 3) * 8;
            const int wrow = (tid >> 2) * 40 + (tid & 3) * 8;
            f32x4 oa[3][2];
#pragma unroll
            for (int n = 0; n < 3; ++n)
#pragma unroll
                for (int m = 0; m < 2; ++m) oa[n][m] = (f32x4){0.f, 0.f, 0.f, 0.f};

            *(int4*)&Wb0[wrow]            = *(const int4*)(gq);
            *(int4*)&Wb0[wrow + 128 * 40] = *(const int4*)(gq + 128 * 256);
            *(int4*)&Wb0[wrow + 256 * 40] = *(const int4*)(gq + 256 * 256);

#pragma unroll
            for (int ks = 0; ks < 8; ++ks) {
                u16* cb = (ks & 1) ? Wb1 : Wb0;
                u16* nb = (ks & 1) ? Wb0 : Wb1;
                int4 q0, q1, q2;
                const bool more = (ks < 7);
                if (more) {
                    q0 = *(const int4*)(gq + (ks + 1) * 32);
                    q1 = *(const int4*)(gq + 128 * 256 + (ks + 1) * 32);
                    q2 = *(const int4*)(gq + 256 * 256 + (ks + 1) * 32);
                }
                __syncthreads();
                bf16x8 wf[3], af2[2];
#pragma unroll
                for (int n = 0; n < 3; ++n)
                    wf[n] = *(const bf16x8*)&cb[(wv * 48 + n * 16 + fr) * 40 + kg * 8];
#pragma unroll
                for (int m = 0; m < 2; ++m)
                    af2[m] = *(const bf16x8*)&actS[(m * 16 + fr) * ACT_P + ks * 32 + kg * 8];
#pragma unroll
                for (int n = 0; n < 3; ++n)
#pragma unroll
                    for (int m = 0; m < 2; ++m)
                        oa[n][m] = __builtin_amdgcn_mfma_f32_16x16x32_bf16(wf[n], af2[m], oa[n][m], 0, 0, 0);
                if (more) {
                    *(int4*)&nb[wrow]            = q0;
                    *(int4*)&nb[wrow + 128 * 40] = q1;
                    *(int4*)&nb[wrow + 256 * 40] = q2;
                }
            }
            // dump acc(+bias) -> outS
#pragma unroll
            for (int n = 0; n < 3; ++n) {
                const int c = wv * 48 + n * 16 + kg * 4;
                const float4 bs = *(const float4*)&BOl[ch * 384 + c];
#pragma unroll
                for (int m = 0; m < 2; ++m) {
                    const int rl = m * 16 + fr;
                    short4 q;
                    q.x = (short)f2bf(oa[n][m][0] + bs.x);
                    q.y = (short)f2bf(oa[n][m][1] + bs.y);
                    q.z = (short)f2bf(oa[n][m][2] + bs.z);
                    q.w = (short)f2bf(oa[n][m][3] + bs.w);
                    *(short4*)&outS[rl * OUTS_P + c] = q;
                }
            }
            __syncthreads();

            // ---- spline: 256 splines x 2 threads (fi=0: w-axis, fi=1: h) ----
            {
                const int sp = tid >> 1, fi = tid & 1;
                const int r = sp & 31, f8 = sp >> 5;
                const int fg = ch * 8 + f8;
                const u16* o_ = &outS[r * OUTS_P + f8 * 48];
                float xin = xfC[r * XF_P + fg];
                bool inside = (xin >= -10.f) && (xin <= 10.f);
                float xs = fminf(fmaxf(xin, -10.f), 10.f);

                float e[16];
                {
                    bf16x8 a = *(const bf16x8*)(o_ + fi * 16);
                    bf16x8 b2 = *(const bf16x8*)(o_ + fi * 16 + 8);
#pragma unroll
                    for (int i = 0; i < 8; ++i) {
                        e[i]     = bf2f((u16)a[i])  * 0.0625f;
                        e[8 + i] = bf2f((u16)b2[i]) * 0.0625f;
                    }
                }
                float mx = e[0];
#pragma unroll
                for (int i = 1; i < 16; ++i) mx = fmaxf(mx, e[i]);
                float s = 0.f;
#pragma unroll
                for (int i = 0; i < 16; ++i) { e[i] = __expf(e[i] - mx); s += e[i]; }
                const float kk = 20.f * (1.f - 1.6e-7f) / s;

                int selk = 0;
                float icw = -10.f, iw = 1.f, ich = -10.f, ih = 1.f;
                if (fi == 0) {
                    float ck = -10.f;
#pragma unroll
                    for (int k = 0; k < 16; ++k) {
                        float c1 = (k == 15) ? 10.f : ck + (2e-7f + kk * e[k]);
                        if (xs >= ck) { selk = k; icw = ck; iw = c1 - ck; }
                        ck = c1;
                    }
                }
                selk = __shfl(selk, lane & ~1);
                if (fi == 1) {
                    float ck = -10.f;
#pragma unroll
                    for (int k = 0; k < 16; ++k) {
                        float c1 = (k == 15) ? 10.f : ck + (2e-7f + kk * e[k]);
                        if (k == selk) { ich = ck; ih = c1 - ck; }
                        ck = c1;
                    }
                }
                ich = __shfl(ich, lane | 1);
                ih  = __shfl(ih,  lane | 1);
                if (fi == 0) {
                    float udl = (selk >= 1)  ? bf2f(o_[32 + selk - 1]) : 0.f;
                    float udr = (selk <= 14) ? bf2f(o_[32 + selk])     : 0.f;
                    float d0 = (selk == 0)  ? 1.f : 1e-8f + splusf(udl);
                    float d1 = (selk == 15) ? 1.f : 1e-8f + splusf(udr);
                    float delta = ih / iw;
                    float t = (xs - icw) / iw;
                    float tt = t * (1.f - t);
                    float denom = delta + (d0 + d1 - 2.f * delta) * tt;
                    float y = ich + ih * (delta * t * t + d0 * tt) / denom;
                    float omt = 1.f - t;
                    float dnum = delta * delta * (d1 * t * t + 2.f * delta * tt + d0 * omt * omt);
                    float ldv = __logf(dnum) - 2.f * __logf(denom);
                    if (!inside) { y = xin; ldv = 0.f; }
                    xfN[r * XF_P + (63 - fg)] = y;
                    if (l == 7) XC[(size_t)(b0 + r) * 64 + fg] = y;
                    ldpart[f8][r] = ldv;
                }
            }
            __syncthreads();
            if (tid < 32) {
                float sld = ldtot[tid];
#pragma unroll
                for (int w8 = 0; w8 < 8; ++w8) sld += ldpart[w8][tid];
                ldtot[tid] = sld;
            }
        } // chunks
    } // layers

    __syncthreads();
    if (tid < 32) LD[b0 + tid] = ldtot[tid];
}

// ---------------------------------------------------------------------------
// finals: stick-breaking + per-sample objective, then reduction
// ---------------------------------------------------------------------------
__global__ __launch_bounds__(256) void final1(
    const float* __restrict__ X, const float* __restrict__ z,
    const float* __restrict__ LD, const float* __restrict__ DM,
    float* __restrict__ PART)
{
    int tid = threadIdx.x;
    int b = blockIdx.x * 256 + tid;
    float ldt = LD[b];
    float pre = 0.f, lvs = 0.f, wls = 0.f, lp = 0.f, tdm = 0.f, tsq = 0.f;
    const float LCLIP = -23.02585093f;
    for (int i = 0; i < 64; ++i) {
        float xi = X[(size_t)b * 64 + i];
        float lv = -splusf(-xi), l1 = -splusf(xi);
        float lt = lv + pre;
        float th = __expf(lt);
        lp += fmaxf(lt, LCLIP);
        tdm += th * DM[i]; tsq += th * th;
        lvs += lv; wls += (float)(64 - i) * l1;
        pre += l1;
    }
    float th = __expf(pre);
    lp += fmaxf(pre, LCLIP); tdm += th * DM[64]; tsq += th * th;
    float zs = 0.f;
    for (int i = 0; i < 64; ++i) { float zz = z[(size_t)b * 64 + i]; zs += zz * zz; }
    float logqz = -0.5f * zs - 58.812066f;
    float log_q = logqz - (ldt + lvs + wls);
    float log_lik = -0.5f * (DM[65] - 2.f * tdm + tsq);
    float val = log_q - lp - log_lik;

    __shared__ float red[256];
    red[tid] = val; __syncthreads();
    for (int s = 128; s > 0; s >>= 1) {
        if (tid < s) red[tid] += red[tid + s];
        __syncthreads();
    }
    if (tid == 0) PART[blockIdx.x] = red[0];
}

__global__ __launch_bounds__(64) void final2(const float* __restrict__ PART,
                                             float* __restrict__ out)
{
    int tid = threadIdx.x;
    float s = (tid < 32) ? PART[tid] : 0.f;
    for (int o = 16; o > 0; o >>= 1) s += __shfl_down(s, o);
    if (tid == 0) out[0] = s * (1.f / 8192.f);
}

// ---------------------------------------------------------------------------
extern "C" void kernel_launch(void* const* d_in, const int* in_sizes, int n_in,
                              void* d_out, int out_size, void* d_ws, size_t ws_size,
                              hipStream_t stream)
{
    (void)in_sizes; (void)n_in; (void)out_size; (void)ws_size;
    const float* z    = (const float*)d_in[0];
    const float* eta  = (const float*)d_in[1];
    const float* dat  = (const float*)d_in[2];
    const float* Win  = (const float*)d_in[3];
    const float* bin  = (const float*)d_in[4];
    const float* Wctx = (const float*)d_in[5];
    const float* bctx = (const float*)d_in[6];
    const float* Wblk = (const float*)d_in[7];
    const float* bblk = (const float*)d_in[8];
    const float* Wout = (const float*)d_in[9];
    const float* bout = (const float*)d_in[10];
    float* out = (float*)d_out;

    char* w = (char*)d_ws;
    size_t off = 0;
    auto alloc = [&](size_t bytes) {
        void* p = w + off;
        off += (bytes + 255) & ~(size_t)255;
        return p;
    };
    u16*   W1  = (u16*)  alloc(8L * 256 * 96 * 2);
    float* B1  = (float*)alloc(8L * 256 * 4);
    u16*   WB  = (u16*)  alloc(8L * 4 * 256 * 256 * 2);
    u16*   WO  = (u16*)  alloc(8L * 3072 * 256 * 2);
    float* BO  = (float*)alloc(8L * 3072 * 4);
    float* XC  = (float*)alloc(8192L * 64 * 4);
    float* LD  = (float*)alloc(8192L * 4);
    float* DM  = (float*)alloc(66 * 4);
    float* PART= (float*)alloc(64 * 4);

    setup_w<<<dim3(2048), dim3(256), 0, stream>>>(
        Win, bin, Wctx, bctx, Wblk, Wout, bout, W1, B1, WB, WO, BO);
    dstat<<<dim3(1), dim3(128), 0, stream>>>(dat, DM);
    flow_all<<<dim3(256), dim3(512), 0, stream>>>(
        z, eta, W1, B1, WB, bblk, WO, BO, XC, LD);
    final1<<<dim3(32), dim3(256), 0, stream>>>(XC, z, LD, DM, PART);
    final2<<<dim3(1), dim3(64), 0, stream>>>(PART, out);
}

// Round 6
// 417.849 us; speedup vs baseline: 1.2684x; 1.2684x over previous
//
#include <hip/hip_runtime.h>
#include <math.h>

typedef float f32x4 __attribute__((ext_vector_type(4)));
typedef short bf16x8 __attribute__((ext_vector_type(8)));
typedef unsigned short u16;

typedef const __attribute__((address_space(1))) unsigned int ga_u32;
typedef __attribute__((address_space(3))) unsigned int ls_u32;

// async global->LDS 16B per lane (dest = wave-uniform base + lane*16)
__device__ __forceinline__ void gl16(const void* g, void* l) {
    __builtin_amdgcn_global_load_lds((ga_u32*)g, (ls_u32*)l, 16, 0, 0);
}

__device__ __forceinline__ u16 f2bf(float f) {
    union { float f; unsigned u; } v; v.f = f;
    return (u16)((v.u + 0x7FFFu + ((v.u >> 16) & 1u)) >> 16);
}
__device__ __forceinline__ float bf2f(u16 h) {
    union { unsigned u; float f; } v; v.u = ((unsigned)h) << 16;
    return v.f;
}
__device__ __forceinline__ float splusf(float x) {
    return fmaxf(x, 0.f) + __logf(1.f + __expf(-fabsf(x)));
}

// ---------------------------------------------------------------------------
// setup: build masked bf16 weights (+padded Wo), fused biases, eta->AXE cols
// ---------------------------------------------------------------------------
__global__ __launch_bounds__(256) void setup_w(
    const float* __restrict__ Win, const float* __restrict__ bin,
    const float* __restrict__ Wctx, const float* __restrict__ bctx,
    const float* __restrict__ Wblk, const float* __restrict__ Wout,
    const float* __restrict__ bout, const float* __restrict__ eta,
    u16* __restrict__ W1, float* __restrict__ B1, u16* __restrict__ WB,
    u16* __restrict__ WO, float* __restrict__ BO, u16* __restrict__ AXE)
{
    const long N1 = 8L * 256 * 96;
    const long N2 = 8L * 256;
    const long N3 = 8L * 4 * 256 * 256;
    const long N4 = 8L * 3072 * 256;
    const long N5 = 8L * 3072;
    const long N6 = 8192L * 32;
    const long tot = N1 + N2 + N3 + N4 + N5 + N6;
    for (long i = (long)blockIdx.x * blockDim.x + threadIdx.x; i < tot;
         i += (long)gridDim.x * blockDim.x) {
        long t = i;
        if (t < N1) {
            long l = t / (256 * 96); long r = t % (256 * 96);
            int j = (int)(r / 96), c = (int)(r % 96);
            float v;
            if (c < 64) v = Win[(l * 256 + j) * 64 + c] * (((j % 63) >= c) ? 1.f : 0.f);
            else        v = Wctx[(l * 256 + j) * 32 + (c - 64)];
            W1[i] = f2bf(v);
        } else if ((t -= N1) < N2) {
            B1[t] = bin[t] + bctx[t];
        } else if ((t -= N2) < N3) {
            int rr = (int)((t / 256) % 256);
            int c = (int)(t % 256);
            float v = Wblk[t] * (((rr % 63) >= (c % 63)) ? 1.f : 0.f);
            WB[t] = f2bf(v);
        } else if ((t -= N3) < N4) {
            long l = t / (3072 * 256); long r = t % (3072 * 256);
            int op = (int)(r / 256), j = (int)(r % 256);
            int fd = op / 48, mm = op % 48;
            float v = 0.f;
            if (mm < 47 && fd > (j % 63))
                v = Wout[(l * 3008 + (long)fd * 47 + mm) * 256 + j];
            WO[t] = f2bf(v);
        } else if ((t -= N4) < N5) {
            long l = t / 3072; int op = (int)(t % 3072);
            int fd = op / 48, mm = op % 48;
            BO[t] = (mm < 47) ? bout[l * 3008 + (long)fd * 47 + mm] : 0.f;
        } else {
            t -= N5;
            long b = t / 32; int p = (int)(t % 32);
            AXE[b * 96 + 64 + p] = f2bf(eta[t]);
        }
    }
}

// ---------------------------------------------------------------------------
// data stats
// ---------------------------------------------------------------------------
__global__ __launch_bounds__(128) void dstat(const float* __restrict__ D,
                                             float* __restrict__ DM)
{
    int j = threadIdx.x;
    float s = 0.f, q = 0.f;
    if (j < 65) {
        for (int m = 0; m < 256; ++m) {
            float v = D[m * 65 + j];
            s += v; q += v * v;
        }
        DM[j] = s * (1.f / 256.f);
    }
    __shared__ float red[128];
    red[j] = q; __syncthreads();
    for (int st = 64; st > 0; st >>= 1) {
        if (j < st) red[j] += red[j + st];
        __syncthreads();
    }
    if (j == 0) DM[65] = red[0] * (1.f / 256.f);
}

// ---------------------------------------------------------------------------
// prep0: flip z -> XF (f32) + AXE cols 0..63 (bf16)
// ---------------------------------------------------------------------------
__global__ __launch_bounds__(256) void prep0(
    const float* __restrict__ z, float* __restrict__ XF, u16* __restrict__ AXE)
{
    size_t gt = (size_t)blockIdx.x * 256 + threadIdx.x;
    size_t b = gt >> 6; int f = (int)(gt & 63);
    float v = z[b * 64 + (63 - f)];
    XF[gt] = v;
    AXE[b * 96 + f] = f2bf(v);
}

// ---------------------------------------------------------------------------
// fused_mid: all 5 mid GEMMs, one kernel/layer. 256 blocks x 32 rows, 512 thr.
// Weights stream global->LDS via global_load_lds (linear [256][32] u16 tiles,
// double-buffered). H in VGPRs across stages; act in LDS (pitch 264).
// ---------------------------------------------------------------------------
#define MID_ACT_P 264

template<int NK>
__device__ __forceinline__ void mid_stage(
    const u16* __restrict__ Wsrc, int wpitch,
    u16* __restrict__ Wq,              // 2 x 8192 u16
    const u16* __restrict__ act,
    int tid, int fr, int kg, int ch0, f32x4 (&acc)[2][2])
{
    const u16* gW = Wsrc + (tid & 3) * 8;
    const int r0 = tid >> 2;

    // prologue: stage ks=0 -> buf0 (2 x 8KB rounds)
    gl16(gW + (size_t)r0 * wpitch,         &Wq[tid * 8]);
    gl16(gW + (size_t)(128 + r0) * wpitch, &Wq[4096 + tid * 8]);

#pragma unroll
    for (int ks = 0; ks < NK; ++ks) {
        __syncthreads();   // drains gloads of buf[ks&1]; orders buffer reuse
        if (ks + 1 < NK) {
            u16* nb = Wq + ((ks + 1) & 1) * 8192;
            gl16(gW + (size_t)r0 * wpitch + (ks + 1) * 32,         &nb[tid * 8]);
            gl16(gW + (size_t)(128 + r0) * wpitch + (ks + 1) * 32, &nb[4096 + tid * 8]);
        }
        const u16* cb = Wq + (ks & 1) * 8192;
        bf16x8 wf0 = *(const bf16x8*)&cb[(ch0 + fr) * 32 + kg * 8];
        bf16x8 wf1 = *(const bf16x8*)&cb[(ch0 + 16 + fr) * 32 + kg * 8];
        bf16x8 af0 = *(const bf16x8*)&act[fr * MID_ACT_P + ks * 32 + kg * 8];
        bf16x8 af1 = *(const bf16x8*)&act[(16 + fr) * MID_ACT_P + ks * 32 + kg * 8];
        acc[0][0] = __builtin_amdgcn_mfma_f32_16x16x32_bf16(wf0, af0, acc[0][0], 0, 0, 0);
        acc[0][1] = __builtin_amdgcn_mfma_f32_16x16x32_bf16(wf0, af1, acc[0][1], 0, 0, 0);
        acc[1][0] = __builtin_amdgcn_mfma_f32_16x16x32_bf16(wf1, af0, acc[1][0], 0, 0, 0);
        acc[1][1] = __builtin_amdgcn_mfma_f32_16x16x32_bf16(wf1, af1, acc[1][1], 0, 0, 0);
    }
    __syncthreads();   // all reads done; caller may overwrite act / Wq
}

__global__ __launch_bounds__(512) void fused_mid(
    const u16* __restrict__ AXE, const u16* __restrict__ W1l,
    const float* __restrict__ B1l, const u16* __restrict__ WBl,
    const float* __restrict__ bbl, u16* __restrict__ HB)
{
    __shared__ u16 Wq[2 * 8192];          // 32768 B
    __shared__ u16 act[32 * MID_ACT_P];   // 16896 B
    const int tid = threadIdx.x;
    const int lane = tid & 63;
    const int wv = tid >> 6;
    const int fr = lane & 15, kg = lane >> 4;
    const int b0 = blockIdx.x * 32;
    const int ch0 = wv * 32;

    // stage-0 activations: AXE rows b0..b0+31 (96 u16 each)
    for (int i = tid; i < 384; i += 512) {
        int row = i / 12, part = i - row * 12;
        *(int4*)&act[row * MID_ACT_P + part * 8] =
            *(const int4*)&AXE[(size_t)(b0 + row) * 96 + part * 8];
    }

    f32x4 H[2][2], T[2][2];

    auto zeroT = [&]() {
#pragma unroll
        for (int m = 0; m < 2; ++m)
#pragma unroll
            for (int n = 0; n < 2; ++n) T[m][n] = (f32x4){0.f, 0.f, 0.f, 0.f};
    };
    auto epi = [&](const float* bias, int mode) {
#pragma unroll
        for (int m = 0; m < 2; ++m) {
            const int cb = ch0 + m * 16 + kg * 4;
            const float4 bs = *(const float4*)&bias[cb];
#pragma unroll
            for (int n = 0; n < 2; ++n) {
                f32x4 v = T[m][n];
                v[0] += bs.x; v[1] += bs.y; v[2] += bs.z; v[3] += bs.w;
                if (mode == 0) H[m][n] = v;
                if (mode == 2 || mode == 3) {
                    H[m][n][0] += v[0]; H[m][n][1] += v[1];
                    H[m][n][2] += v[2]; H[m][n][3] += v[3];
                    v = H[m][n];
                }
                short4 q;
                if (mode != 3) {
                    q.x = (short)f2bf(fmaxf(v[0], 0.f));
                    q.y = (short)f2bf(fmaxf(v[1], 0.f));
                    q.z = (short)f2bf(fmaxf(v[2], 0.f));
                    q.w = (short)f2bf(fmaxf(v[3], 0.f));
                    *(short4*)&act[(n * 16 + fr) * MID_ACT_P + cb] = q;
                } else {
                    q.x = (short)f2bf(v[0]); q.y = (short)f2bf(v[1]);
                    q.z = (short)f2bf(v[2]); q.w = (short)f2bf(v[3]);
                    *(short4*)&HB[(size_t)(b0 + n * 16 + fr) * 256 + cb] = q;
                }
            }
        }
    };

    zeroT();
    mid_stage<3>(W1l, 96, Wq, act, tid, fr, kg, ch0, T);
    epi(B1l, 0);
    zeroT();
    mid_stage<8>(WBl, 256, Wq, act, tid, fr, kg, ch0, T);
    epi(bbl, 1);
    zeroT();
    mid_stage<8>(WBl + 65536, 256, Wq, act, tid, fr, kg, ch0, T);
    epi(bbl + 256, 2);
    zeroT();
    mid_stage<8>(WBl + 2 * 65536, 256, Wq, act, tid, fr, kg, ch0, T);
    epi(bbl + 2 * 256, 1);
    zeroT();
    mid_stage<8>(WBl + 3 * 65536, 256, Wq, act, tid, fr, kg, ch0, T);
    epi(bbl + 3 * 256, 3);
}

// ---------------------------------------------------------------------------
// Out-GEMM (128x96 tile, K=256) + fused RQS spline.
// A/B staged via global_load_lds into linear [row][32] u16 tiles, dbuf.
// Swapped-operand MFMA (lane holds batch row fr, 4 consecutive cols).
// LDS 28 KB -> 5 blocks/CU. Acc dump (pitch 104) aliases the staging bufs.
// ---------------------------------------------------------------------------
__global__ __launch_bounds__(256) void gemm_out_spline(
    const u16* __restrict__ A, const u16* __restrict__ Wo,
    const float* __restrict__ bo, const float* __restrict__ XF,
    float* __restrict__ Xn, float* __restrict__ XFnext, u16* __restrict__ AXE,
    float* __restrict__ LDP, int first)
{
    __shared__ u16 SM[14336];   // A dbuf 2x4096 | B dbuf 2x3072 (28672 B)
    const int tid = threadIdx.x;
    const int lane = tid & 63, wv = tid >> 6;
    const int wm = wv >> 1, wn = wv & 1;
    const int fr = lane & 15, kg = lane >> 4;
    const int m0 = blockIdx.x * 128, n0 = blockIdx.y * 96;

    const u16* gA = A  + (size_t)m0 * 256 + (tid & 3) * 8;
    const u16* gB = Wo + (size_t)n0 * 256 + (tid & 3) * 8;
    const int r4 = tid >> 2;

    f32x4 acc[4][3];
#pragma unroll
    for (int m = 0; m < 4; ++m)
#pragma unroll
        for (int n = 0; n < 3; ++n) acc[m][n] = (f32x4){0.f, 0.f, 0.f, 0.f};

    // prologue: stage ks=0 into buf0
    gl16(gA + (size_t)r4 * 256,        &SM[tid * 8]);
    gl16(gA + (size_t)(64 + r4) * 256, &SM[2048 + tid * 8]);
    gl16(gB + (size_t)r4 * 256,        &SM[8192 + tid * 8]);
    if (tid < 128)
        gl16(gB + (size_t)(64 + r4) * 256, &SM[8192 + 2048 + tid * 8]);

#pragma unroll
    for (int ks = 0; ks < 8; ++ks) {
        __syncthreads();   // drains buf[ks&1] gloads; orders buffer reuse
        if (ks < 7) {
            const int kt = (ks + 1) * 32;
            u16* An = SM + ((ks + 1) & 1) * 4096;
            u16* Bn = SM + 8192 + ((ks + 1) & 1) * 3072;
            gl16(gA + (size_t)r4 * 256 + kt,        &An[tid * 8]);
            gl16(gA + (size_t)(64 + r4) * 256 + kt, &An[2048 + tid * 8]);
            gl16(gB + (size_t)r4 * 256 + kt,        &Bn[tid * 8]);
            if (tid < 128)
                gl16(gB + (size_t)(64 + r4) * 256 + kt, &Bn[2048 + tid * 8]);
        }
        const u16* Ac = SM + (ks & 1) * 4096;
        const u16* Bc = SM + 8192 + (ks & 1) * 3072;
        bf16x8 af[4], bf[3];
#pragma unroll
        for (int m = 0; m < 4; ++m)
            af[m] = *(const bf16x8*)&Ac[(wm * 64 + m * 16 + fr) * 32 + kg * 8];
#pragma unroll
        for (int n = 0; n < 3; ++n)
            bf[n] = *(const bf16x8*)&Bc[(wn * 48 + n * 16 + fr) * 32 + kg * 8];
#pragma unroll
        for (int m = 0; m < 4; ++m)
#pragma unroll
            for (int n = 0; n < 3; ++n)
                acc[m][n] = __builtin_amdgcn_mfma_f32_16x16x32_bf16(bf[n], af[m], acc[m][n], 0, 0, 0);
    }
    __syncthreads();   // all frag reads done before dump aliases the buffers

    // dump acc(+bias) as bf16, pitch 104 u16, b64 stores (4 cols per lane)
#pragma unroll
    for (int m = 0; m < 4; ++m) {
        const int row = wm * 64 + m * 16 + fr;
#pragma unroll
        for (int n = 0; n < 3; ++n) {
            const int c0 = wn * 48 + n * 16 + kg * 4;
            const float4 bs = *(const float4*)&bo[n0 + c0];
            short4 q;
            q.x = (short)f2bf(acc[m][n][0] + bs.x);
            q.y = (short)f2bf(acc[m][n][1] + bs.y);
            q.z = (short)f2bf(acc[m][n][2] + bs.z);
            q.w = (short)f2bf(acc[m][n][3] + bs.w);
            *(short4*)&SM[row * 104 + c0] = q;
        }
    }
    __syncthreads();

    // ---- RQS spline: one thread per (row, feature); 256 = 128 x 2 ----
    const int r = tid >> 1, fi = tid & 1;
    const int b = m0 + r;
    const int fg = blockIdx.y * 2 + fi;
    const u16* o_ = &SM[r * 104 + fi * 48];
    bf16x8 v0 = *(const bf16x8*)(o_);
    bf16x8 v1 = *(const bf16x8*)(o_ + 8);
    bf16x8 v2 = *(const bf16x8*)(o_ + 16);
    bf16x8 v3 = *(const bf16x8*)(o_ + 24);
    bf16x8 v4 = *(const bf16x8*)(o_ + 32);
    bf16x8 v5 = *(const bf16x8*)(o_ + 40);

    float xin = XF[(size_t)b * 64 + fg];
    bool inside = (xin >= -10.f) && (xin <= 10.f);
    float xs = fminf(fmaxf(xin, -10.f), 10.f);

    float ew[16], eh[16], ud[15];
#pragma unroll
    for (int i = 0; i < 8; ++i) {
        ew[i]     = bf2f((u16)v0[i]) * 0.0625f;
        ew[8 + i] = bf2f((u16)v1[i]) * 0.0625f;
        eh[i]     = bf2f((u16)v2[i]) * 0.0625f;
        eh[8 + i] = bf2f((u16)v3[i]) * 0.0625f;
    }
#pragma unroll
    for (int i = 0; i < 8; ++i) ud[i] = bf2f((u16)v4[i]);
#pragma unroll
    for (int i = 0; i < 7; ++i) ud[8 + i] = bf2f((u16)v5[i]);

    float mw = ew[0], mh = eh[0];
#pragma unroll
    for (int i = 1; i < 16; ++i) { mw = fmaxf(mw, ew[i]); mh = fmaxf(mh, eh[i]); }
    float sw = 0.f, sh = 0.f;
#pragma unroll
    for (int i = 0; i < 16; ++i) {
        ew[i] = __expf(ew[i] - mw); sw += ew[i];
        eh[i] = __expf(eh[i] - mh); sh += eh[i];
    }
    const float kw = 20.f * (1.f - 1.6e-7f) / sw;
    const float kh = 20.f * (1.f - 1.6e-7f) / sh;

    float cwk = -10.f, chk = -10.f;
    float icw = -10.f, ich = -10.f, iw = 1.f, ih = 1.f, udl = 0.f, udr = 0.f;
    int selk = 0;
#pragma unroll
    for (int k = 0; k < 16; ++k) {
        const float cw1 = (k == 15) ? 10.f : cwk + (2e-7f + kw * ew[k]);
        const float ch1 = (k == 15) ? 10.f : chk + (2e-7f + kh * eh[k]);
        if (xs >= cwk) {
            selk = k;
            icw = cwk; iw = cw1 - cwk;
            ich = chk; ih = ch1 - chk;
            udl = (k >= 1)  ? ud[k - 1] : 0.f;
            udr = (k <= 14) ? ud[k]     : 0.f;
        }
        cwk = cw1; chk = ch1;
    }
    float d0 = (selk == 0)  ? 1.f : 1e-8f + splusf(udl);
    float d1 = (selk == 15) ? 1.f : 1e-8f + splusf(udr);
    float delta = ih / iw;
    float t = (xs - icw) / iw;
    float tt = t * (1.f - t);
    float denom = delta + (d0 + d1 - 2.f * delta) * tt;
    float y = ich + ih * (delta * t * t + d0 * tt) / denom;
    float omt = 1.f - t;
    float dnum = delta * delta * (d1 * t * t + 2.f * delta * tt + d0 * omt * omt);
    float ldv = __logf(dnum) - 2.f * __logf(denom);
    if (!inside) { y = xin; ldv = 0.f; }

    Xn[(size_t)b * 64 + fg] = y;
    XFnext[(size_t)b * 64 + (63 - fg)] = y;
    AXE[(size_t)b * 96 + (63 - fg)] = f2bf(y);

    float other = __shfl_xor(ldv, 1);
    if (fi == 0) {
        size_t o = (size_t)b * 32 + blockIdx.y;
        float v = ldv + other;
        LDP[o] = first ? v : (LDP[o] + v);
    }
}

// ---------------------------------------------------------------------------
// finals: stick-breaking + per-sample objective, then reduction
// ---------------------------------------------------------------------------
__global__ __launch_bounds__(256) void final1(
    const float* __restrict__ X, const float* __restrict__ z,
    const float* __restrict__ LDP, const float* __restrict__ DM,
    float* __restrict__ PART)
{
    int tid = threadIdx.x;
    int b = blockIdx.x * 256 + tid;
    float ldt = 0.f;
    for (int g = 0; g < 32; ++g) ldt += LDP[(size_t)b * 32 + g];
    float pre = 0.f, lvs = 0.f, wls = 0.f, lp = 0.f, tdm = 0.f, tsq = 0.f;
    const float LCLIP = -23.02585093f;
    for (int i = 0; i < 64; ++i) {
        float xi = X[(size_t)b * 64 + i];
        float lv = -splusf(-xi), l1 = -splusf(xi);
        float lt = lv + pre;
        float th = __expf(lt);
        lp += fmaxf(lt, LCLIP);
        tdm += th * DM[i]; tsq += th * th;
        lvs += lv; wls += (float)(64 - i) * l1;
        pre += l1;
    }
    float th = __expf(pre);
    lp += fmaxf(pre, LCLIP); tdm += th * DM[64]; tsq += th * th;
    float zs = 0.f;
    for (int i = 0; i < 64; ++i) { float zz = z[(size_t)b * 64 + i]; zs += zz * zz; }
    float logqz = -0.5f * zs - 58.812066f;
    float log_q = logqz - (ldt + lvs + wls);
    float log_lik = -0.5f * (DM[65] - 2.f * tdm + tsq);
    float val = log_q - lp - log_lik;

    __shared__ float red[256];
    red[tid] = val; __syncthreads();
    for (int s = 128; s > 0; s >>= 1) {
        if (tid < s) red[tid] += red[tid + s];
        __syncthreads();
    }
    if (tid == 0) PART[blockIdx.x] = red[0];
}

__global__ __launch_bounds__(64) void final2(const float* __restrict__ PART,
                                             float* __restrict__ out)
{
    int tid = threadIdx.x;
    float s = (tid < 32) ? PART[tid] : 0.f;
    for (int o = 16; o > 0; o >>= 1) s += __shfl_down(s, o);
    if (tid == 0) out[0] = s * (1.f / 8192.f);
}

// ---------------------------------------------------------------------------
extern "C" void kernel_launch(void* const* d_in, const int* in_sizes, int n_in,
                              void* d_out, int out_size, void* d_ws, size_t ws_size,
                              hipStream_t stream)
{
    (void)in_sizes; (void)n_in; (void)out_size; (void)ws_size;
    const float* z    = (const float*)d_in[0];
    const float* eta  = (const float*)d_in[1];
    const float* dat  = (const float*)d_in[2];
    const float* Win  = (const float*)d_in[3];
    const float* bin  = (const float*)d_in[4];
    const float* Wctx = (const float*)d_in[5];
    const float* bctx = (const float*)d_in[6];
    const float* Wblk = (const float*)d_in[7];
    const float* bblk = (const float*)d_in[8];
    const float* Wout = (const float*)d_in[9];
    const float* bout = (const float*)d_in[10];
    float* out = (float*)d_out;

    char* w = (char*)d_ws;
    size_t off = 0;
    auto alloc = [&](size_t bytes) {
        void* p = w + off;
        off += (bytes + 255) & ~(size_t)255;
        return p;
    };
    u16*   W1  = (u16*)  alloc(8L * 256 * 96 * 2);
    float* B1  = (float*)alloc(8L * 256 * 4);
    u16*   WB  = (u16*)  alloc(8L * 4 * 256 * 256 * 2);
    u16*   WO  = (u16*)  alloc(8L * 3072 * 256 * 2);
    float* BO  = (float*)alloc(8L * 3072 * 4);
    u16*   AXE = (u16*)  alloc(8192L * 96 * 2);
    float* XFa = (float*)alloc(8192L * 64 * 4);
    float* XFb = (float*)alloc(8192L * 64 * 4);
    float* XC  = (float*)alloc(8192L * 64 * 4);
    u16*   HB  = (u16*)  alloc(8192L * 256 * 2);
    float* LDP = (float*)alloc(8192L * 32 * 4);
    float* DM  = (float*)alloc(66 * 4);
    float* PART= (float*)alloc(64 * 4);

    setup_w<<<dim3(2048), dim3(256), 0, stream>>>(
        Win, bin, Wctx, bctx, Wblk, Wout, bout, eta, W1, B1, WB, WO, BO, AXE);
    dstat<<<dim3(1), dim3(128), 0, stream>>>(dat, DM);
    prep0<<<dim3(2048), dim3(256), 0, stream>>>(z, XFa, AXE);

    for (int l = 0; l < 8; ++l) {
        float* XFin  = (l & 1) ? XFb : XFa;
        float* XFout = (l & 1) ? XFa : XFb;
        fused_mid<<<dim3(256), dim3(512), 0, stream>>>(
            AXE, W1 + (size_t)l * 256 * 96, B1 + l * 256,
            WB + (size_t)l * 4 * 65536, bblk + (size_t)l * 4 * 256, HB);
        gemm_out_spline<<<dim3(64, 32), dim3(256), 0, stream>>>(
            HB, WO + (size_t)l * 3072 * 256, BO + l * 3072, XFin,
            XC, XFout, AXE, LDP, (l == 0) ? 1 : 0);
    }
    final1<<<dim3(32), dim3(256), 0, stream>>>(XC, z, LDP, DM, PART);
    final2<<<dim3(1), dim3(64), 0, stream>>>(PART, out);
}